// Round 9
// baseline (505.154 us; speedup 1.0000x reference)
//
#include <hip/hip_runtime.h>
#include <hip/hip_bf16.h>
#include <math.h>

#define HDIM 128
#define TPB 256

typedef __attribute__((ext_vector_type(8))) short bf16x8;
typedef __attribute__((ext_vector_type(4))) float f32x4;

static inline int ceil_div(int a, int b){ return (a + b - 1) / b; }

__device__ __forceinline__ float wave_sum(float v){
#pragma unroll
  for (int o = 32; o > 0; o >>= 1) v += __shfl_down(v, o, 64);
  return v;
}
__device__ __forceinline__ int wave_sum_i(int v){
#pragma unroll
  for (int o = 32; o > 0; o >>= 1) v += __shfl_down(v, o, 64);
  return v;
}

__device__ __forceinline__ short f2bf(float f){
  __hip_bfloat16 h = __float2bfloat16(f);
  return *reinterpret_cast<short*>(&h);
}
__device__ __forceinline__ float bfb2f(short s){
  unsigned int u = ((unsigned int)(unsigned short)s) << 16;
  return __builtin_bit_cast(float, u);
}

// async global->LDS: 64 lanes x 16B; LDS dest is wave-uniform base (+lane*16 by HW)
__device__ __forceinline__ void gl_lds16(const short* g, short* l){
  __builtin_amdgcn_global_load_lds(
      (const __attribute__((address_space(1))) void*)g,
      (__attribute__((address_space(3))) void*)l, 16, 0, 0);
}

// ---------------------------------------------------------------------------
// prep_a: fused csr_hist | node_stats | pack_weights
// ---------------------------------------------------------------------------
__global__ void prep_a(const int* __restrict__ rcv, int* __restrict__ deg, int E, int neb,
                       const float* __restrict__ zl, const float* __restrict__ zt,
                       float* __restrict__ npart, int N, int nnb,
                       const float* __restrict__ encEW2,
                       const float* __restrict__ encNW2,
                       const float* __restrict__ decW1,
                       const float* __restrict__ beW1,
                       const float* __restrict__ beW2,
                       const float* __restrict__ bnW1,
                       const float* __restrict__ bnW2,
                       __hip_bfloat16* __restrict__ wp){
  __shared__ float red[4][12];
  const int bx = blockIdx.x, tid = threadIdx.x;
  if (bx < neb){
    int e = bx * 256 + tid;
    if (e < E) atomicAdd(&deg[rcv[e]], 1);
    return;
  }
  if (bx < neb + nnb){
    int b = bx - neb;
    int w = tid >> 6, l = tid & 63;
    int n = b * 256 + tid;
    float s[12];
#pragma unroll
    for (int i = 0; i < 12; i++) s[i] = 0.f;
    if (n < N){
#pragma unroll
      for (int d = 0; d < 3; d++){
        float z = zl[3*n+d];
        float t = zt[3*n+d] - z;
        s[d]   = z;  s[3+d] = z*z;
        s[6+d] = t;  s[9+d] = t*t;
      }
    }
#pragma unroll
    for (int i = 0; i < 12; i++) s[i] = wave_sum(s[i]);
    if (l == 0)
#pragma unroll
      for (int i = 0; i < 12; i++) red[w][i] = s[i];
    __syncthreads();
    if (tid < 12)
      npart[(size_t)b * 12 + tid] =
        red[0][tid] + red[1][tid] + red[2][tid] + red[3][tid];
    return;
  }
  // pack_weights region: fp32 [K][128] -> bf16 fragment-major
  int pid = bx - neb - nnb;
  int y = pid / 192;
  int x = pid - y * 192;
  const float* src; __hip_bfloat16* dst; int K;
  if (y == 0){ src = encEW2; dst = wp;          K = 128; }
  else if (y == 1){ src = encNW2; dst = wp + 16384; K = 128; }
  else if (y == 2){ src = decW1;  dst = wp + 32768; K = 128; }
  else {
    int b = (y - 3) >> 2, j = (y - 3) & 3;
    __hip_bfloat16* base = wp + 49152 + b * 114688;
    if (j == 0){ src = beW1 + b*49152; dst = base;          K = 384; }
    else if (j == 1){ src = beW2 + b*16384; dst = base + 49152; K = 128; }
    else if (j == 2){ src = bnW1 + b*32768; dst = base + 65536; K = 256; }
    else { src = bnW2 + b*16384; dst = base + 98304; K = 128; }
  }
  int id = x * 256 + tid;
  if (id >= 128 * K) return;
  int c = id >> 12;
  int r = id & 4095;
  int t = r >> 9;
  int l = (r >> 3) & 63;
  int j = r & 7;
  int k = c * 32 + ((l >> 4) << 3) + j;
  int n = t * 16 + (l & 15);
  dst[id] = __float2bfloat16(src[k * 128 + n]);
}

// ---------------------------------------------------------------------------
// scan pass1: per-1024-block sums of deg
// ---------------------------------------------------------------------------
__global__ void scan_pass1(const int* __restrict__ deg, int* __restrict__ bsum, int N){
  __shared__ int red[4];
  int tid = threadIdx.x;
  int base = blockIdx.x * 1024;
  int s = 0;
  for (int i = tid; i < 1024; i += 256){
    int idx = base + i;
    if (idx < N) s += deg[idx];
  }
  s = wave_sum_i(s);
  if ((tid & 63) == 0) red[tid >> 6] = s;
  __syncthreads();
  if (tid == 0) bsum[blockIdx.x] = red[0] + red[1] + red[2] + red[3];
}

// ---------------------------------------------------------------------------
// scan pass3 (pass2 folded): writes the scatter cursor
// ---------------------------------------------------------------------------
__global__ void scan_pass3(const int* __restrict__ deg, const int* __restrict__ bsum,
                           int nsb, int* __restrict__ cursor, int N){
  __shared__ int tsum[256];
  __shared__ int base_s;
  int tid = threadIdx.x;
  if (tid == 0){
    int acc = 0;
    for (int b = 0; b < (int)blockIdx.x; b++) acc += bsum[b];
    base_s = acc;
  }
  int base = blockIdx.x * 1024;
  int i0 = base + tid * 4;
  int v[4];
  int s = 0;
#pragma unroll
  for (int k = 0; k < 4; k++){
    int idx = i0 + k;
    v[k] = (idx < N) ? deg[idx] : 0;
    s += v[k];
  }
  tsum[tid] = s;
  __syncthreads();
  for (int off = 1; off < 256; off <<= 1){
    int val = (tid >= off) ? tsum[tid - off] : 0;
    __syncthreads();
    tsum[tid] += val;
    __syncthreads();
  }
  int excl = (tid == 0) ? 0 : tsum[tid - 1];
  int b = base_s + excl;
#pragma unroll
  for (int k = 0; k < 4; k++){
    int idx = i0 + k;
    if (idx < N){
      cursor[idx] = b;
      b += v[k];
    }
  }
}

// ---------------------------------------------------------------------------
// Edge prep (R5 plain form): permutation scatter + raw features + stats
// ---------------------------------------------------------------------------
__global__ void edge_prep(const float* __restrict__ pos,
                          const int* __restrict__ snd,
                          const int* __restrict__ rcv,
                          int* __restrict__ cursor,
                          int* __restrict__ psnd,
                          int* __restrict__ prcv,
                          float* __restrict__ ef_raw,
                          float* __restrict__ epart, int E){
  __shared__ float red[4][6];
  int tid = threadIdx.x, w = tid >> 6, l = tid & 63;
  int e = blockIdx.x * blockDim.x + tid;
  float s[6] = {0.f,0.f,0.f,0.f,0.f,0.f};
  if (e < E){
    int si = snd[e], ri = rcv[e];
    int p = atomicAdd(&cursor[ri], 1);
    psnd[p] = si;
    prcv[p] = ri;
    float rx = pos[2*si]   - pos[2*ri];
    float ry = pos[2*si+1] - pos[2*ri+1];
    float nm = sqrtf(rx*rx + ry*ry);
    ef_raw[3*p]   = rx;
    ef_raw[3*p+1] = ry;
    ef_raw[3*p+2] = nm;
    s[0] = rx; s[1] = ry; s[2] = nm;
    s[3] = rx*rx; s[4] = ry*ry; s[5] = nm*nm;
  }
#pragma unroll
  for (int k = 0; k < 6; k++) s[k] = wave_sum(s[k]);
  if (l == 0)
#pragma unroll
    for (int k = 0; k < 6; k++) red[w][k] = s[k];
  __syncthreads();
  if (tid < 6)
    epart[(size_t)blockIdx.x * 6 + tid] =
      red[0][tid] + red[1][tid] + red[2][tid] + red[3][tid];
}

// ---------------------------------------------------------------------------
// Reduce partials + finalize stats (R5 standalone).
// fin: em[0..2] es[3..5] nm[6..8] ns[9..11] om[12..14] os[15..17]
// ---------------------------------------------------------------------------
__global__ void reduce_finalize(const float* __restrict__ ep, int ne,
                                const float* __restrict__ np_, int nn,
                                float* __restrict__ fin, int E, int N){
  __shared__ float red[4];
  __shared__ float raw[18];
  int tid = threadIdx.x, w = tid >> 6, l = tid & 63;
  for (int j = 0; j < 6; j++){
    float s = 0.f;
    for (int b = tid; b < ne; b += 256) s += ep[(size_t)b * 6 + j];
    s = wave_sum(s);
    if (l == 0) red[w] = s;
    __syncthreads();
    if (tid == 0) raw[j] = red[0] + red[1] + red[2] + red[3];
    __syncthreads();
  }
  for (int j = 0; j < 12; j++){
    float s = 0.f;
    for (int b = tid; b < nn; b += 256) s += np_[(size_t)b * 12 + j];
    s = wave_sum(s);
    if (l == 0) red[w] = s;
    __syncthreads();
    if (tid == 0) raw[6 + j] = red[0] + red[1] + red[2] + red[3];
    __syncthreads();
  }
  if (tid == 0){
#pragma unroll
    for (int d = 0; d < 3; d++){
      float cE = (float)E, cN = (float)N;
      float m, v;
      m = raw[0+d] / cE; v = fmaxf(raw[3+d]/cE - m*m, 0.f);
      fin[0+d] = m;  fin[3+d]  = fmaxf(sqrtf(v), 1e-8f);
      m = raw[6+d] / cN; v = fmaxf(raw[9+d]/cN - m*m, 0.f);
      fin[6+d] = m;  fin[9+d]  = fmaxf(sqrtf(v), 1e-8f);
      m = raw[12+d] / cN; v = fmaxf(raw[15+d]/cN - m*m, 0.f);
      fin[12+d] = m; fin[15+d] = fmaxf(sqrtf(v), 1e-8f);
    }
  }
}

// ---------------------------------------------------------------------------
// Fused encoder (R9: W2 B-fragments direct from L2 — no LDS, no barriers)
// ---------------------------------------------------------------------------
__launch_bounds__(256)
__global__ void encoder_both(const float* __restrict__ eraw,
                             const float* __restrict__ zl,
                             const float* __restrict__ fin,
                             const float* __restrict__ eW1, const float* __restrict__ eb1,
                             const float* __restrict__ nW1, const float* __restrict__ nb1,
                             const __hip_bfloat16* __restrict__ wp, // W2e @0, W2n @16384
                             const float* __restrict__ eb2, const float* __restrict__ nb2,
                             __hip_bfloat16* __restrict__ efo, __hip_bfloat16* __restrict__ nfo,
                             int E, int N, int EB){
  const int tid = threadIdx.x, w = tid >> 6, l = tid & 63, m = l & 15, q = l >> 4;
  const bool ise = ((int)blockIdx.x < EB);
  const float* raw = ise ? eraw : zl;
  const float* mptr = fin + (ise ? 0 : 6);
  const float* sptr = fin + (ise ? 3 : 9);
  const float* W1 = ise ? eW1 : nW1;
  const float* b1 = ise ? eb1 : nb1;
  const float* b2 = ise ? eb2 : nb2;
  const short* wsrc = (const short*)wp + (ise ? 0 : 16384);
  __hip_bfloat16* out = ise ? efo : nfo;
  const int rows = ise ? E : N;
  const int bx = ise ? (int)blockIdx.x : (int)blockIdx.x - EB;
  float s0 = mptr[0], s1 = mptr[1], s2 = mptr[2];
  float d0 = sptr[0], d1 = sptr[1], d2 = sptr[2];
  const int row0 = bx * 64 + w * 16;
  const int ra = min(row0 + m, rows - 1);
  float x0 = (raw[3*ra]   - s0) / d0;
  float x1 = (raw[3*ra+1] - s1) / d1;
  float x2 = (raw[3*ra+2] - s2) / d2;
  bf16x8 afr[4];
#pragma unroll
  for (int c = 0; c < 4; c++){
    int nb = c * 32 + q * 8;
#pragma unroll
    for (int j = 0; j < 8; j++){
      float h = b1[nb+j] + x0 * W1[nb+j] + x1 * W1[128+nb+j] + x2 * W1[256+nb+j];
      afr[c][j] = f2bf(fmaxf(h, 0.f));
    }
  }
  f32x4 acc[8];
#pragma unroll
  for (int t = 0; t < 8; t++) acc[t] = (f32x4){0.f,0.f,0.f,0.f};
#pragma unroll
  for (int c = 0; c < 4; c++){
#pragma unroll
    for (int t = 0; t < 8; t++){
      bf16x8 b = *(const bf16x8*)(wsrc + (c*8 + t)*512 + l*8);
      acc[t] = __builtin_amdgcn_mfma_f32_16x16x32_bf16(afr[c], b, acc[t], 0, 0, 0);
    }
  }
  const int row_d = row0 + q * 4;
#pragma unroll
  for (int t = 0; t < 8; t++){
    int col = t * 16 + m;
    float bb = b2[col];
#pragma unroll
    for (int r = 0; r < 4; r++){
      int e = row_d + r;
      if (e < rows) out[(size_t)e * HDIM + col] = __float2bfloat16(acc[t][r] + bb);
    }
  }
}

// ---------------------------------------------------------------------------
// msg_pre (R9): u = nf @ [W1s|W1r] with B direct from L2.
// NO LDS, NO barriers — removes the staging-drain serialization that made
// this 22us/launch. Also zeroes agg for this round.
// ---------------------------------------------------------------------------
__launch_bounds__(256)
__global__ void msg_pre(const __hip_bfloat16* __restrict__ nf,
                        const __hip_bfloat16* __restrict__ eWf, // full eW1 frag-major
                        __hip_bfloat16* __restrict__ u,
                        float* __restrict__ agg, int N){
  const int tid = threadIdx.x, w = tid >> 6, l = tid & 63, m = l & 15, q = l >> 4;
  const short* ws = (const short*)eWf + 4 * 4096;   // sender half (chunks 4..7)
  const short* wr_ = (const short*)eWf + 8 * 4096;  // receiver half (chunks 8..11)
  // zero agg slice for this block's 64 nodes (padded buffer)
  {
    float* az = agg + (size_t)blockIdx.x * 8192;
#pragma unroll
    for (int i = 0; i < 8; i++)
      *(f32x4*)(az + (size_t)(i * 256 + tid) * 4) = (f32x4){0.f,0.f,0.f,0.f};
  }
  const int row0 = blockIdx.x * 64 + w * 16;
  const int ra = min(row0 + m, N - 1);
  const short* pa = (const short*)nf + (size_t)ra * HDIM + q * 8;
  bf16x8 afr[4];
#pragma unroll
  for (int c = 0; c < 4; c++) afr[c] = *(const bf16x8*)(pa + c * 32);
  f32x4 acc[8];
#pragma unroll
  for (int t = 0; t < 8; t++) acc[t] = (f32x4){0.f,0.f,0.f,0.f};
#pragma unroll
  for (int c = 0; c < 4; c++)
#pragma unroll
    for (int t = 0; t < 8; t++){
      bf16x8 b = *(const bf16x8*)(ws + (c*8 + t)*512 + l*8);
      acc[t] = __builtin_amdgcn_mfma_f32_16x16x32_bf16(afr[c], b, acc[t], 0, 0, 0);
    }
  const int row_d = row0 + q * 4;
#pragma unroll
  for (int t = 0; t < 8; t++){
    int col = t * 16 + m;
#pragma unroll
    for (int r = 0; r < 4; r++){
      int n = row_d + r;
      if (n < N) u[(size_t)n * 256 + col] = __float2bfloat16(acc[t][r]);
    }
  }
#pragma unroll
  for (int t = 0; t < 8; t++) acc[t] = (f32x4){0.f,0.f,0.f,0.f};
#pragma unroll
  for (int c = 0; c < 4; c++)
#pragma unroll
    for (int t = 0; t < 8; t++){
      bf16x8 b = *(const bf16x8*)(wr_ + (c*8 + t)*512 + l*8);
      acc[t] = __builtin_amdgcn_mfma_f32_16x16x32_bf16(afr[c], b, acc[t], 0, 0, 0);
    }
#pragma unroll
  for (int t = 0; t < 8; t++){
    int col = 128 + t * 16 + m;
#pragma unroll
    for (int r = 0; r < 4; r++){
      int n = row_d + r;
      if (n < N) u[(size_t)n * 256 + col] = __float2bfloat16(acc[t][r]);
    }
  }
}

// ---------------------------------------------------------------------------
// Edge block (R5 final form, UNTOUCHED — proven 54us): 3-barrier GEMM
// structure + register-batched block-level segment reduce.
// ---------------------------------------------------------------------------
__launch_bounds__(512)
__global__ void edge_block(const int* __restrict__ psnd,
                           const int* __restrict__ prcv,
                           const __hip_bfloat16* __restrict__ u,   // [n][256] bf16
                           __hip_bfloat16* __restrict__ ef,
                           const __hip_bfloat16* __restrict__ Wfrag, // eW1|eW2 frag-major
                           const float* __restrict__ b1,
                           const float* __restrict__ b2,
                           float* __restrict__ agg,                 // [N][128] f32, zeroed
                           int do_write, int E){
  __shared__ __align__(16) short bsh[16384];       // 32 KB: W1e, then W2
  __shared__ __align__(16) short hsh[8][16][136];  // 34.8 KB
  __shared__ int rsh[128];                         // receiver per block-edge
  const int tid = threadIdx.x, w = tid >> 6, l = tid & 63, m = l & 15, q = l >> 4;
  const short* wsrc = (const short*)Wfrag;
  const int row0 = blockIdx.x * 128 + w * 16;
  const int grow = min(row0 + (l >> 2), E - 1);
  const int us_row = psnd[grow], ur_row = prcv[grow];
  if ((l & 3) == 0) rsh[w * 16 + (l >> 2)] = ur_row;
#pragma unroll
  for (int i = 0; i < 4; i++){
    int inst = i * 8 + w;
    gl_lds16(wsrc + inst * 512 + l * 8, &bsh[inst * 512]);
  }
  const int ra = min(row0 + m, E - 1);
  const short* pe = (const short*)ef + (size_t)ra * HDIM + q * 8;
  bf16x8 afr[4];
#pragma unroll
  for (int c = 0; c < 4; c++) afr[c] = *(const bf16x8*)(pe + c * 32);
  {
    const short* pus = (const short*)u + (size_t)us_row * 256 + (l & 3) * 32;
    const short* pur = (const short*)u + (size_t)ur_row * 256 + 128 + (l & 3) * 32;
    short* hdst = &hsh[w][l >> 2][(l & 3) * 32];
#pragma unroll
    for (int k = 0; k < 4; k++){
      bf16x8 a = *(const bf16x8*)(pus + k * 8);
      bf16x8 b = *(const bf16x8*)(pur + k * 8);
      bf16x8 s;
#pragma unroll
      for (int j = 0; j < 8; j++) s[j] = f2bf(bfb2f(a[j]) + bfb2f(b[j]));
      *(bf16x8*)(hdst + k * 8) = s;
    }
  }
  f32x4 acc[8];
#pragma unroll
  for (int t = 0; t < 8; t++) acc[t] = (f32x4){0.f,0.f,0.f,0.f};
  __syncthreads();                               // B1: W1e + u-sums ready
#pragma unroll
  for (int c = 0; c < 4; c++){
#pragma unroll
    for (int t = 0; t < 8; t++){
      bf16x8 b = *(const bf16x8*)&bsh[(c*8 + t)*512 + l*8];
      acc[t] = __builtin_amdgcn_mfma_f32_16x16x32_bf16(afr[c], b, acc[t], 0, 0, 0);
    }
  }
  __syncthreads();                               // B2: all waves done with W1e
#pragma unroll
  for (int i = 0; i < 4; i++){
    int inst = i * 8 + w;
    gl_lds16(wsrc + 49152 + inst * 512 + l * 8, &bsh[inst * 512]);
  }
#pragma unroll
  for (int t = 0; t < 8; t++){
    float bb = b1[t * 16 + m];
#pragma unroll
    for (int r = 0; r < 4; r++){
      float uval = bfb2f(hsh[w][q*4 + r][t*16 + m]);
      hsh[w][q*4 + r][t*16 + m] = f2bf(fmaxf(acc[t][r] + uval + bb, 0.f));
    }
  }
  __syncthreads();                               // B3: W2 staged, h ready
  bf16x8 ah[4];
  const short* ph = &hsh[w][m][0] + q * 8;
#pragma unroll
  for (int c = 0; c < 4; c++) ah[c] = *(const bf16x8*)(ph + c * 32);
#pragma unroll
  for (int t = 0; t < 8; t++) acc[t] = (f32x4){0.f,0.f,0.f,0.f};
#pragma unroll
  for (int c = 0; c < 4; c++){
#pragma unroll
    for (int t = 0; t < 8; t++){
      bf16x8 b = *(const bf16x8*)&bsh[(c*8 + t)*512 + l*8];
      acc[t] = __builtin_amdgcn_mfma_f32_16x16x32_bf16(ah[c], b, acc[t], 0, 0, 0);
    }
  }
#pragma unroll
  for (int t = 0; t < 8; t++){
    float bb = b2[t * 16 + m];
#pragma unroll
    for (int r = 0; r < 4; r++)
      hsh[w][q*4 + r][t*16 + m] = f2bf(acc[t][r] + bb);
  }
  const int orow = row0 + (l >> 2);
  const int orc = min(orow, E - 1);
  const short* pold = (const short*)ef + (size_t)orc * HDIM + (l & 3) * 32;
  short* hslot = &hsh[w][l >> 2][(l & 3) * 32];
  short* dst = (short*)ef + (size_t)orc * HDIM + (l & 3) * 32;
  const bool wr = (orow < E) && do_write;
#pragma unroll
  for (int k = 0; k < 4; k++){
    bf16x8 vnew = *(const bf16x8*)(hslot + k * 8);
    bf16x8 vo   = *(const bf16x8*)(pold + k * 8);
    bf16x8 vr;
#pragma unroll
    for (int j = 0; j < 8; j++) vr[j] = f2bf(bfb2f(vnew[j]) + bfb2f(vo[j]));
    *(bf16x8*)(hslot + k * 8) = vr;
    if (wr) *(bf16x8*)(dst + k * 8) = vr;
  }
  __syncthreads();                               // B4: hsh finalized block-wide
  {
    const int c = tid & 127;          // column
    const int g = tid >> 7;           // group 0..3 (uniform per wave)
    const int nval = min(128, E - (int)blockIdx.x * 128);
    const int e0 = g * 32;
    if (e0 < nval){
      const int e1 = min(e0 + 32, nval);
      float run = 0.f; int cur = -1; int runstart = e0;
#pragma unroll
      for (int half = 0; half < 2; half++){
        float v[16]; int rv[16];
#pragma unroll
        for (int k = 0; k < 16; k++){
          int e = e0 + half * 16 + k;
          v[k]  = bfb2f(hsh[(e >> 4) & 7][e & 15][c]);
          rv[k] = rsh[e & 127];
        }
#pragma unroll
        for (int k = 0; k < 16; k++){
          int e = e0 + half * 16 + k;
          if (e < e1){                           // wave-uniform
            if (rv[k] != cur){                   // wave-uniform
              if (cur >= 0){
                if (runstart == e0) atomicAdd(&agg[(size_t)cur * 128 + c], run);
                else                agg[(size_t)cur * 128 + c] = run;
              }
              cur = rv[k]; run = 0.f; runstart = e;
            }
            run += v[k];
          }
        }
      }
      atomicAdd(&agg[(size_t)cur * 128 + c], run);
    }
  }
}

// ---------------------------------------------------------------------------
// Node block (R9): dense agg read; W1/W2 B-fragments direct from L2 —
// drops all 6 staging barriers, keeps only the h-transpose barrier.
// ---------------------------------------------------------------------------
__launch_bounds__(256)
__global__ void node_block(const float* __restrict__ agg,   // [N][128] f32
                           __hip_bfloat16* __restrict__ nf,
                           const __hip_bfloat16* __restrict__ Wfrag, // nW1|nW2
                           const float* __restrict__ b1,
                           const float* __restrict__ b2,
                           int N){
  __shared__ __align__(16) short hsh[4][16][136];   // 17.4 KB
  const int tid = threadIdx.x, w = tid >> 6, l = tid & 63, m = l & 15, q = l >> 4;
  const short* wg = (const short*)Wfrag;            // nW1: 8 chunks
  const short* w2 = wg + 32768;                     // nW2: 4 chunks

  const int row0 = blockIdx.x * 64 + w * 16;
  const int ra = min(row0 + m, N - 1);
  const short* pn = (const short*)nf + (size_t)ra * HDIM + q * 8;
  bf16x8 afr[8];
#pragma unroll
  for (int c = 0; c < 4; c++) afr[c] = *(const bf16x8*)(pn + c * 32);

  // dense agg read (coalesced)
  const float* pag = agg + (size_t)ra * 128 + q * 8;
#pragma unroll
  for (int c = 0; c < 4; c++){
    f32x4 a0 = *(const f32x4*)(pag + c * 32);
    f32x4 a1 = *(const f32x4*)(pag + c * 32 + 4);
#pragma unroll
    for (int j = 0; j < 4; j++){
      afr[4 + c][j]     = f2bf(a0[j]);
      afr[4 + c][4 + j] = f2bf(a1[j]);
    }
  }

  f32x4 acc[8];
#pragma unroll
  for (int t = 0; t < 8; t++) acc[t] = (f32x4){0.f,0.f,0.f,0.f};
  // GEMM1: K=256, B from L2 (64 coalesced 16B loads/lane, broadcast-shared)
#pragma unroll
  for (int c = 0; c < 8; c++){
#pragma unroll
    for (int t = 0; t < 8; t++){
      bf16x8 b = *(const bf16x8*)(wg + (c*8 + t)*512 + l*8);
      acc[t] = __builtin_amdgcn_mfma_f32_16x16x32_bf16(afr[c], b, acc[t], 0, 0, 0);
    }
  }
#pragma unroll
  for (int t = 0; t < 8; t++){
    float bb = b1[t * 16 + m];
#pragma unroll
    for (int r = 0; r < 4; r++)
      hsh[w][q*4 + r][t*16 + m] = f2bf(fmaxf(acc[t][r] + bb, 0.f));
  }
  __syncthreads();                   // h-transpose visibility (sole barrier)
  const short* ph = &hsh[w][m][0] + q * 8;
#pragma unroll
  for (int t = 0; t < 8; t++) acc[t] = (f32x4){0.f,0.f,0.f,0.f};
#pragma unroll
  for (int c = 0; c < 4; c++){
    bf16x8 a = *(const bf16x8*)(ph + c * 32);
#pragma unroll
    for (int t = 0; t < 8; t++){
      bf16x8 b = *(const bf16x8*)(w2 + (c*8 + t)*512 + l*8);
      acc[t] = __builtin_amdgcn_mfma_f32_16x16x32_bf16(a, b, acc[t], 0, 0, 0);
    }
  }
  __syncthreads();                   // all GEMM2 hsh reads done before rewrite
#pragma unroll
  for (int t = 0; t < 8; t++){
    float bb = b2[t * 16 + m];
#pragma unroll
    for (int r = 0; r < 4; r++)
      hsh[w][q*4 + r][t*16 + m] = f2bf(acc[t][r] + bb);
  }
  const int orow = row0 + (l >> 2);
  if (orow < N){
    const short* pold = (const short*)nf + (size_t)orow * HDIM + (l & 3) * 32;
    const short* src = &hsh[w][l >> 2][(l & 3) * 32];
    short* dst = (short*)nf + (size_t)orow * HDIM + (l & 3) * 32;
#pragma unroll
    for (int k = 0; k < 4; k++){
      bf16x8 vnew = *(const bf16x8*)(src + k * 8);
      bf16x8 vo   = *(const bf16x8*)(pold + k * 8);
      bf16x8 vr;
#pragma unroll
      for (int j = 0; j < 8; j++) vr[j] = f2bf(bfb2f(vnew[j]) + bfb2f(vo[j]));
      *(bf16x8*)(dst + k * 8) = vr;
    }
  }
}

// ---------------------------------------------------------------------------
// dec_fused (R9): decW1 B direct from L2, dec W2 [128][3] f32 direct.
// Only the loss-reduction barriers remain.
// ---------------------------------------------------------------------------
__launch_bounds__(256)
__global__ void dec_fused(const __hip_bfloat16* __restrict__ A,   // nf
                          const __hip_bfloat16* __restrict__ Wf,  // decW1 frag-major
                          const float* __restrict__ b1,
                          const float* __restrict__ W2,            // [128][3]
                          const float* __restrict__ b2,            // [3]
                          const float* __restrict__ zl,
                          const float* __restrict__ z_target,
                          const float* __restrict__ fin,
                          float* __restrict__ d_out,
                          float* __restrict__ lred,                // 4 floats, zeroed
                          unsigned int* __restrict__ cnt,          // zeroed
                          int N){
  __shared__ float red[4][4];
  const int tid = threadIdx.x, w = tid >> 6, l = tid & 63, m = l & 15, q = l >> 4;
  const short* wg = (const short*)Wf;
  const int row0 = blockIdx.x * 64 + w * 16;
  const int ra = min(row0 + m, N - 1);
  const short* pa = (const short*)A + (size_t)ra * HDIM + q * 8;
  bf16x8 afr[4];
#pragma unroll
  for (int c = 0; c < 4; c++) afr[c] = *(const bf16x8*)(pa + c * 32);
  f32x4 acc[8];
#pragma unroll
  for (int t = 0; t < 8; t++) acc[t] = (f32x4){0.f,0.f,0.f,0.f};
#pragma unroll
  for (int c = 0; c < 4; c++){
#pragma unroll
    for (int t = 0; t < 8; t++){
      bf16x8 b = *(const bf16x8*)(wg + (c*8 + t)*512 + l*8);
      acc[t] = __builtin_amdgcn_mfma_f32_16x16x32_bf16(afr[c], b, acc[t], 0, 0, 0);
    }
  }
  float p0[4] = {0,0,0,0}, p1[4] = {0,0,0,0}, p2[4] = {0,0,0,0};
#pragma unroll
  for (int t = 0; t < 8; t++){
    int col = t * 16 + m;
    float bb = b1[col];
    float w0 = W2[col*3], w1 = W2[col*3+1], w2v = W2[col*3+2];
#pragma unroll
    for (int r = 0; r < 4; r++){
      float h = fmaxf(acc[t][r] + bb, 0.f);
      p0[r] += h * w0; p1[r] += h * w1; p2[r] += h * w2v;
    }
  }
#pragma unroll
  for (int r = 0; r < 4; r++){
#pragma unroll
    for (int o = 1; o < 16; o <<= 1){
      p0[r] += __shfl_xor(p0[r], o, 64);
      p1[r] += __shfl_xor(p1[r], o, 64);
      p2[r] += __shfl_xor(p2[r], o, 64);
    }
  }
  float s[4] = {0.f,0.f,0.f,0.f};
  if (m == 0){
#pragma unroll
    for (int r = 0; r < 4; r++){
      int n = row0 + q * 4 + r;
      if (n < N){
        float pd[3] = {p0[r], p1[r], p2[r]};
#pragma unroll
        for (int d = 0; d < 3; d++){
          float o   = pd[d] + b2[d];
          float om = fin[12 + d], os = fin[15 + d];
          float zld = zl[3*n + d];
          float zt  = z_target[3*n + d];
          float tn  = ((zt - zld) - om) / os;
          float diff = tn - o;
          s[0] += diff * diff;
          float zp = zld + o * os + om;
          d_out[3*n + d] = zp;
          float e = zp - zt;
          s[1 + d] += e * e;
        }
      }
    }
  }
#pragma unroll
  for (int k = 0; k < 4; k++) s[k] = wave_sum(s[k]);
  if (l == 0)
#pragma unroll
    for (int k = 0; k < 4; k++) red[w][k] = s[k];
  __syncthreads();
  if (tid < 4)
    atomicAdd(&lred[tid], red[0][tid] + red[1][tid] + red[2][tid] + red[3][tid]);
  __syncthreads();
  if (tid == 0){
    __threadfence();
    unsigned int t = atomicAdd(cnt, 1u);
    if (t == gridDim.x - 1){
      float vals[4];
#pragma unroll
      for (int k = 0; k < 4; k++) vals[k] = atomicAdd(&lred[k], 0.f);
      float cN = (float)N;
      float loss = vals[0] / (3.f * cN);
      float rmse = (sqrtf(vals[1]/cN) + sqrtf(vals[2]/cN) + sqrtf(vals[3]/cN)) / 3.f;
      d_out[(size_t)3 * N]     = loss;
      d_out[(size_t)3 * N + 1] = rmse;
    }
  }
}

// ---------------------------------------------------------------------------
extern "C" void kernel_launch(void* const* d_in, const int* in_sizes, int n_in,
                              void* d_out, int out_size, void* d_ws, size_t ws_size,
                              hipStream_t stream){
  const float* z           = (const float*)d_in[0];
  const float* z_target    = (const float*)d_in[1];
  const float* pos         = (const float*)d_in[2];
  const float* enc_node_W1 = (const float*)d_in[3];
  const float* enc_node_b1 = (const float*)d_in[4];
  const float* enc_node_W2 = (const float*)d_in[5];
  const float* enc_node_b2 = (const float*)d_in[6];
  const float* enc_edge_W1 = (const float*)d_in[7];
  const float* enc_edge_b1 = (const float*)d_in[8];
  const float* enc_edge_W2 = (const float*)d_in[9];
  const float* enc_edge_b2 = (const float*)d_in[10];
  const float* dec_W1      = (const float*)d_in[11];
  const float* dec_b1      = (const float*)d_in[12];
  const float* dec_W2      = (const float*)d_in[13];
  const float* dec_b2      = (const float*)d_in[14];
  const float* blk_edge_W1 = (const float*)d_in[15];
  const float* blk_edge_b1 = (const float*)d_in[16];
  const float* blk_edge_W2 = (const float*)d_in[17];
  const float* blk_edge_b2 = (const float*)d_in[18];
  const float* blk_node_W1 = (const float*)d_in[19];
  const float* blk_node_b1 = (const float*)d_in[20];
  const float* blk_node_W2 = (const float*)d_in[21];
  const float* blk_node_b2 = (const float*)d_in[22];
  const int*   senders     = (const int*)d_in[23];
  const int*   receivers   = (const int*)d_in[24];

  const int N = in_sizes[1] / 3;
  const int E = in_sizes[23];
  const float* zl = z + (size_t)N * 3;

  const int neb = ceil_div(E, TPB);
  const int nnb = ceil_div(N, TPB);
  const int nsb = ceil_div(N, 1024);   // scan blocks
  const int EB  = ceil_div(E, 64);
  const int NB  = ceil_div(N, 64);

  char* p = (char*)d_ws;
  auto carve = [&](size_t bytes) -> char* {
    char* r = p; p += (bytes + 255) & ~(size_t)255; return r;
  };
  float* stats_fin = (float*)carve(32 * 4);
  float* epart     = (float*)carve((size_t)neb * 6 * 4);
  float* npart     = (float*)carve((size_t)nnb * 12 * 4);
  float* ef_raw    = (float*)carve((size_t)E * 3 * 4);
  int*   deg       = (int*)carve((size_t)(N + 16) * 4);   // + lred(4f)+cnt
  float* lred      = (float*)(deg + N);
  unsigned int* cnt = (unsigned int*)(deg + N + 4);
  int*   bsum      = (int*)carve((size_t)(nsb + 1) * 4);
  int*   cursor    = (int*)carve((size_t)N * 4);
  int*   psnd      = (int*)carve((size_t)E * 4);
  int*   prcv      = (int*)carve((size_t)E * 4);
  float* agg       = (float*)carve(((size_t)N + 64) * 128 * 4);  // padded
  __hip_bfloat16* wp = (__hip_bfloat16*)carve((size_t)507904 * 2);
  __hip_bfloat16* ef = (__hip_bfloat16*)carve((size_t)E * HDIM * 2);
  __hip_bfloat16* nf = (__hip_bfloat16*)carve((size_t)N * HDIM * 2);
  __hip_bfloat16* u  = (__hip_bfloat16*)carve((size_t)N * 256 * 2);

  float* out = (float*)d_out;

  hipMemsetAsync(deg, 0, (size_t)(N + 16) * 4, stream);

  prep_a<<<neb + nnb + 3648, TPB, 0, stream>>>(receivers, deg, E, neb,
                                               zl, z_target, npart, N, nnb,
                                               enc_edge_W2, enc_node_W2, dec_W1,
                                               blk_edge_W1, blk_edge_W2,
                                               blk_node_W1, blk_node_W2, wp);
  scan_pass1<<<nsb, TPB, 0, stream>>>(deg, bsum, N);
  scan_pass3<<<nsb, TPB, 0, stream>>>(deg, bsum, nsb, cursor, N);
  edge_prep<<<neb, TPB, 0, stream>>>(pos, senders, receivers, cursor,
                                     psnd, prcv, ef_raw, epart, E);
  reduce_finalize<<<1, TPB, 0, stream>>>(epart, neb, npart, nnb, stats_fin, E, N);

  encoder_both<<<EB + NB, TPB, 0, stream>>>(ef_raw, zl, stats_fin,
                                            enc_edge_W1, enc_edge_b1,
                                            enc_node_W1, enc_node_b1,
                                            wp, enc_edge_b2, enc_node_b2,
                                            ef, nf, E, N, EB);

  for (int b = 0; b < 4; b++){
    const __hip_bfloat16* eWf = wp + 49152 + (size_t)b * 114688;   // eW1|eW2
    const __hip_bfloat16* nWf = eWf + 65536;                       // nW1|nW2
    const float* eb1 = blk_edge_b1 + (size_t)b * 128;
    const float* eb2 = blk_edge_b2 + (size_t)b * 128;
    const float* nb1 = blk_node_b1 + (size_t)b * 128;
    const float* nb2 = blk_node_b2 + (size_t)b * 128;

    msg_pre<<<NB, TPB, 0, stream>>>(nf, eWf, u, agg, N);
    edge_block<<<ceil_div(E, 128), 512, 0, stream>>>(psnd, prcv, u, ef,
                                                     eWf, eb1, eb2, agg,
                                                     (b < 3) ? 1 : 0, E);
    node_block<<<NB, TPB, 0, stream>>>(agg, nf, nWf, nb1, nb2, N);
  }

  dec_fused<<<NB, TPB, 0, stream>>>(nf, wp + 32768, dec_b1, dec_W2, dec_b2,
                                    zl, z_target, stats_fin,
                                    out, lred, cnt, N);
}

// Round 10
// 487.279 us; speedup vs baseline: 1.0367x; 1.0367x over previous
//
#include <hip/hip_runtime.h>
#include <hip/hip_bf16.h>
#include <math.h>

#define HDIM 128
#define TPB 256

typedef __attribute__((ext_vector_type(8))) short bf16x8;
typedef __attribute__((ext_vector_type(4))) float f32x4;

static inline int ceil_div(int a, int b){ return (a + b - 1) / b; }

__device__ __forceinline__ float wave_sum(float v){
#pragma unroll
  for (int o = 32; o > 0; o >>= 1) v += __shfl_down(v, o, 64);
  return v;
}
__device__ __forceinline__ int wave_sum_i(int v){
#pragma unroll
  for (int o = 32; o > 0; o >>= 1) v += __shfl_down(v, o, 64);
  return v;
}

__device__ __forceinline__ short f2bf(float f){
  __hip_bfloat16 h = __float2bfloat16(f);
  return *reinterpret_cast<short*>(&h);
}
__device__ __forceinline__ float bfb2f(short s){
  unsigned int u = ((unsigned int)(unsigned short)s) << 16;
  return __builtin_bit_cast(float, u);
}

// async global->LDS: 64 lanes x 16B; LDS dest is wave-uniform base (+lane*16 by HW)
__device__ __forceinline__ void gl_lds16(const short* g, short* l){
  __builtin_amdgcn_global_load_lds(
      (const __attribute__((address_space(1))) void*)g,
      (__attribute__((address_space(3))) void*)l, 16, 0, 0);
}

// ---------------------------------------------------------------------------
// prep_a: fused csr_hist | node_stats | pack_weights
// ---------------------------------------------------------------------------
__global__ void prep_a(const int* __restrict__ rcv, int* __restrict__ deg, int E, int neb,
                       const float* __restrict__ zl, const float* __restrict__ zt,
                       float* __restrict__ npart, int N, int nnb,
                       const float* __restrict__ encEW2,
                       const float* __restrict__ encNW2,
                       const float* __restrict__ decW1,
                       const float* __restrict__ beW1,
                       const float* __restrict__ beW2,
                       const float* __restrict__ bnW1,
                       const float* __restrict__ bnW2,
                       __hip_bfloat16* __restrict__ wp){
  __shared__ float red[4][12];
  const int bx = blockIdx.x, tid = threadIdx.x;
  if (bx < neb){
    int e = bx * 256 + tid;
    if (e < E) atomicAdd(&deg[rcv[e]], 1);
    return;
  }
  if (bx < neb + nnb){
    int b = bx - neb;
    int w = tid >> 6, l = tid & 63;
    int n = b * 256 + tid;
    float s[12];
#pragma unroll
    for (int i = 0; i < 12; i++) s[i] = 0.f;
    if (n < N){
#pragma unroll
      for (int d = 0; d < 3; d++){
        float z = zl[3*n+d];
        float t = zt[3*n+d] - z;
        s[d]   = z;  s[3+d] = z*z;
        s[6+d] = t;  s[9+d] = t*t;
      }
    }
#pragma unroll
    for (int i = 0; i < 12; i++) s[i] = wave_sum(s[i]);
    if (l == 0)
#pragma unroll
      for (int i = 0; i < 12; i++) red[w][i] = s[i];
    __syncthreads();
    if (tid < 12)
      npart[(size_t)b * 12 + tid] =
        red[0][tid] + red[1][tid] + red[2][tid] + red[3][tid];
    return;
  }
  // pack_weights region: fp32 [K][128] -> bf16 fragment-major
  int pid = bx - neb - nnb;
  int y = pid / 192;
  int x = pid - y * 192;
  const float* src; __hip_bfloat16* dst; int K;
  if (y == 0){ src = encEW2; dst = wp;          K = 128; }
  else if (y == 1){ src = encNW2; dst = wp + 16384; K = 128; }
  else if (y == 2){ src = decW1;  dst = wp + 32768; K = 128; }
  else {
    int b = (y - 3) >> 2, j = (y - 3) & 3;
    __hip_bfloat16* base = wp + 49152 + b * 114688;
    if (j == 0){ src = beW1 + b*49152; dst = base;          K = 384; }
    else if (j == 1){ src = beW2 + b*16384; dst = base + 49152; K = 128; }
    else if (j == 2){ src = bnW1 + b*32768; dst = base + 65536; K = 256; }
    else { src = bnW2 + b*16384; dst = base + 98304; K = 128; }
  }
  int id = x * 256 + tid;
  if (id >= 128 * K) return;
  int c = id >> 12;
  int r = id & 4095;
  int t = r >> 9;
  int l = (r >> 3) & 63;
  int j = r & 7;
  int k = c * 32 + ((l >> 4) << 3) + j;
  int n = t * 16 + (l & 15);
  dst[id] = __float2bfloat16(src[k * 128 + n]);
}

// ---------------------------------------------------------------------------
// scan pass1: per-1024-block sums of deg
// ---------------------------------------------------------------------------
__global__ void scan_pass1(const int* __restrict__ deg, int* __restrict__ bsum, int N){
  __shared__ int red[4];
  int tid = threadIdx.x;
  int base = blockIdx.x * 1024;
  int s = 0;
  for (int i = tid; i < 1024; i += 256){
    int idx = base + i;
    if (idx < N) s += deg[idx];
  }
  s = wave_sum_i(s);
  if ((tid & 63) == 0) red[tid >> 6] = s;
  __syncthreads();
  if (tid == 0) bsum[blockIdx.x] = red[0] + red[1] + red[2] + red[3];
}

// ---------------------------------------------------------------------------
// scan pass3 (pass2 folded): writes the scatter cursor
// ---------------------------------------------------------------------------
__global__ void scan_pass3(const int* __restrict__ deg, const int* __restrict__ bsum,
                           int nsb, int* __restrict__ cursor, int N){
  __shared__ int tsum[256];
  __shared__ int base_s;
  int tid = threadIdx.x;
  if (tid == 0){
    int acc = 0;
    for (int b = 0; b < (int)blockIdx.x; b++) acc += bsum[b];
    base_s = acc;
  }
  int base = blockIdx.x * 1024;
  int i0 = base + tid * 4;
  int v[4];
  int s = 0;
#pragma unroll
  for (int k = 0; k < 4; k++){
    int idx = i0 + k;
    v[k] = (idx < N) ? deg[idx] : 0;
    s += v[k];
  }
  tsum[tid] = s;
  __syncthreads();
  for (int off = 1; off < 256; off <<= 1){
    int val = (tid >= off) ? tsum[tid - off] : 0;
    __syncthreads();
    tsum[tid] += val;
    __syncthreads();
  }
  int excl = (tid == 0) ? 0 : tsum[tid - 1];
  int b = base_s + excl;
#pragma unroll
  for (int k = 0; k < 4; k++){
    int idx = i0 + k;
    if (idx < N){
      cursor[idx] = b;
      b += v[k];
    }
  }
}

// ---------------------------------------------------------------------------
// Edge prep: permutation scatter + raw features (written permuted) + stats
// ---------------------------------------------------------------------------
__global__ void edge_prep(const float* __restrict__ pos,
                          const int* __restrict__ snd,
                          const int* __restrict__ rcv,
                          int* __restrict__ cursor,
                          int* __restrict__ psnd,
                          int* __restrict__ prcv,
                          float* __restrict__ ef_raw,
                          float* __restrict__ epart, int E){
  __shared__ float red[4][6];
  int tid = threadIdx.x, w = tid >> 6, l = tid & 63;
  int e = blockIdx.x * blockDim.x + tid;
  float s[6] = {0.f,0.f,0.f,0.f,0.f,0.f};
  if (e < E){
    int si = snd[e], ri = rcv[e];
    int p = atomicAdd(&cursor[ri], 1);
    psnd[p] = si;
    prcv[p] = ri;
    float rx = pos[2*si]   - pos[2*ri];
    float ry = pos[2*si+1] - pos[2*ri+1];
    float nm = sqrtf(rx*rx + ry*ry);
    ef_raw[3*p]   = rx;
    ef_raw[3*p+1] = ry;
    ef_raw[3*p+2] = nm;
    s[0] = rx; s[1] = ry; s[2] = nm;
    s[3] = rx*rx; s[4] = ry*ry; s[5] = nm*nm;
  }
#pragma unroll
  for (int k = 0; k < 6; k++) s[k] = wave_sum(s[k]);
  if (l == 0)
#pragma unroll
    for (int k = 0; k < 6; k++) red[w][k] = s[k];
  __syncthreads();
  if (tid < 6)
    epart[(size_t)blockIdx.x * 6 + tid] =
      red[0][tid] + red[1][tid] + red[2][tid] + red[3][tid];
}

// ---------------------------------------------------------------------------
// Reduce partials + finalize stats.
// fin: em[0..2] es[3..5] nm[6..8] ns[9..11] om[12..14] os[15..17]
// ---------------------------------------------------------------------------
__global__ void reduce_finalize(const float* __restrict__ ep, int ne,
                                const float* __restrict__ np_, int nn,
                                float* __restrict__ fin, int E, int N){
  __shared__ float red[4];
  __shared__ float raw[18];
  int tid = threadIdx.x, w = tid >> 6, l = tid & 63;
  for (int j = 0; j < 6; j++){
    float s = 0.f;
    for (int b = tid; b < ne; b += 256) s += ep[(size_t)b * 6 + j];
    s = wave_sum(s);
    if (l == 0) red[w] = s;
    __syncthreads();
    if (tid == 0) raw[j] = red[0] + red[1] + red[2] + red[3];
    __syncthreads();
  }
  for (int j = 0; j < 12; j++){
    float s = 0.f;
    for (int b = tid; b < nn; b += 256) s += np_[(size_t)b * 12 + j];
    s = wave_sum(s);
    if (l == 0) red[w] = s;
    __syncthreads();
    if (tid == 0) raw[6 + j] = red[0] + red[1] + red[2] + red[3];
    __syncthreads();
  }
  if (tid == 0){
#pragma unroll
    for (int d = 0; d < 3; d++){
      float cE = (float)E, cN = (float)N;
      float m, v;
      m = raw[0+d] / cE; v = fmaxf(raw[3+d]/cE - m*m, 0.f);
      fin[0+d] = m;  fin[3+d]  = fmaxf(sqrtf(v), 1e-8f);
      m = raw[6+d] / cN; v = fmaxf(raw[9+d]/cN - m*m, 0.f);
      fin[6+d] = m;  fin[9+d]  = fmaxf(sqrtf(v), 1e-8f);
      m = raw[12+d] / cN; v = fmaxf(raw[15+d]/cN - m*m, 0.f);
      fin[12+d] = m; fin[15+d] = fmaxf(sqrtf(v), 1e-8f);
    }
  }
}

// ---------------------------------------------------------------------------
// Fused encoder (edge+node in one launch)
// ---------------------------------------------------------------------------
__launch_bounds__(256)
__global__ void encoder_both(const float* __restrict__ eraw,
                             const float* __restrict__ zl,
                             const float* __restrict__ fin,
                             const float* __restrict__ eW1, const float* __restrict__ eb1,
                             const float* __restrict__ nW1, const float* __restrict__ nb1,
                             const __hip_bfloat16* __restrict__ wp, // W2e @0, W2n @16384
                             const float* __restrict__ eb2, const float* __restrict__ nb2,
                             __hip_bfloat16* __restrict__ efo, __hip_bfloat16* __restrict__ nfo,
                             int E, int N, int EB){
  __shared__ __align__(16) short bsh[16384];
  const int tid = threadIdx.x, w = tid >> 6, l = tid & 63, m = l & 15, q = l >> 4;
  const bool ise = ((int)blockIdx.x < EB);
  const float* raw = ise ? eraw : zl;
  const float* mptr = fin + (ise ? 0 : 6);
  const float* sptr = fin + (ise ? 3 : 9);
  const float* W1 = ise ? eW1 : nW1;
  const float* b1 = ise ? eb1 : nb1;
  const float* b2 = ise ? eb2 : nb2;
  const short* wsrc = (const short*)wp + (ise ? 0 : 16384);
  __hip_bfloat16* out = ise ? efo : nfo;
  const int rows = ise ? E : N;
  const int bx = ise ? (int)blockIdx.x : (int)blockIdx.x - EB;
#pragma unroll
  for (int i = 0; i < 8; i++){
    int inst = w * 8 + i;
    gl_lds16(wsrc + inst * 512 + l * 8, &bsh[inst * 512]);
  }
  float s0 = mptr[0], s1 = mptr[1], s2 = mptr[2];
  float d0 = sptr[0], d1 = sptr[1], d2 = sptr[2];
  const int row0 = bx * 64 + w * 16;
  const int ra = min(row0 + m, rows - 1);
  float x0 = (raw[3*ra]   - s0) / d0;
  float x1 = (raw[3*ra+1] - s1) / d1;
  float x2 = (raw[3*ra+2] - s2) / d2;
  bf16x8 afr[4];
#pragma unroll
  for (int c = 0; c < 4; c++){
    int nb = c * 32 + q * 8;
#pragma unroll
    for (int j = 0; j < 8; j++){
      float h = b1[nb+j] + x0 * W1[nb+j] + x1 * W1[128+nb+j] + x2 * W1[256+nb+j];
      afr[c][j] = f2bf(fmaxf(h, 0.f));
    }
  }
  f32x4 acc[8];
#pragma unroll
  for (int t = 0; t < 8; t++) acc[t] = (f32x4){0.f,0.f,0.f,0.f};
  __syncthreads();
#pragma unroll
  for (int c = 0; c < 4; c++){
#pragma unroll
    for (int t = 0; t < 8; t++){
      bf16x8 b = *(const bf16x8*)&bsh[(c*8 + t)*512 + l*8];
      acc[t] = __builtin_amdgcn_mfma_f32_16x16x32_bf16(afr[c], b, acc[t], 0, 0, 0);
    }
  }
  const int row_d = row0 + q * 4;
#pragma unroll
  for (int t = 0; t < 8; t++){
    int col = t * 16 + m;
    float bb = b2[col];
#pragma unroll
    for (int r = 0; r < 4; r++){
      int e = row_d + r;
      if (e < rows) out[(size_t)e * HDIM + col] = __float2bfloat16(acc[t][r] + bb);
    }
  }
}

// ---------------------------------------------------------------------------
// msg_pre (R5 proven form): u = nf @ [W1s|W1r]; zeroes agg for this round
// ---------------------------------------------------------------------------
__launch_bounds__(256)
__global__ void msg_pre(const __hip_bfloat16* __restrict__ nf,
                        const __hip_bfloat16* __restrict__ eWf, // full eW1 frag-major
                        __hip_bfloat16* __restrict__ u,
                        float* __restrict__ agg, int N){
  __shared__ __align__(16) short wsh[16384];   // 32 KB
  const int tid = threadIdx.x, w = tid >> 6, l = tid & 63, m = l & 15, q = l >> 4;
  const short* wsrc = (const short*)eWf + 4 * 4096;  // chunks 4..7 (sender half)
#pragma unroll
  for (int i = 0; i < 8; i++){
    int f = w * 8 + i;
    gl_lds16(wsrc + f * 512 + l * 8, &wsh[f * 512]);
  }
  {
    float* az = agg + (size_t)blockIdx.x * 8192;
#pragma unroll
    for (int i = 0; i < 8; i++)
      *(f32x4*)(az + (size_t)(i * 256 + tid) * 4) = (f32x4){0.f,0.f,0.f,0.f};
  }
  const int row0 = blockIdx.x * 64 + w * 16;
  const int ra = min(row0 + m, N - 1);
  const short* pa = (const short*)nf + (size_t)ra * HDIM + q * 8;
  bf16x8 afr[4];
#pragma unroll
  for (int c = 0; c < 4; c++) afr[c] = *(const bf16x8*)(pa + c * 32);
  f32x4 acc[8];
#pragma unroll
  for (int t = 0; t < 8; t++) acc[t] = (f32x4){0.f,0.f,0.f,0.f};
  __syncthreads();                    // sender half staged
#pragma unroll
  for (int c = 0; c < 4; c++)
#pragma unroll
    for (int t = 0; t < 8; t++){
      bf16x8 b = *(const bf16x8*)&wsh[(c*8 + t)*512 + l*8];
      acc[t] = __builtin_amdgcn_mfma_f32_16x16x32_bf16(afr[c], b, acc[t], 0, 0, 0);
    }
  const int row_d = row0 + q * 4;
#pragma unroll
  for (int t = 0; t < 8; t++){
    int col = t * 16 + m;
#pragma unroll
    for (int r = 0; r < 4; r++){
      int n = row_d + r;
      if (n < N) u[(size_t)n * 256 + col] = __float2bfloat16(acc[t][r]);
    }
  }
  __syncthreads();                    // all waves done with sender half
#pragma unroll
  for (int i = 0; i < 8; i++){
    int f = w * 8 + i;
    gl_lds16(wsrc + 16384 + f * 512 + l * 8, &wsh[f * 512]);  // chunks 8..11
  }
#pragma unroll
  for (int t = 0; t < 8; t++) acc[t] = (f32x4){0.f,0.f,0.f,0.f};
  __syncthreads();                    // receiver half staged
#pragma unroll
  for (int c = 0; c < 4; c++)
#pragma unroll
    for (int t = 0; t < 8; t++){
      bf16x8 b = *(const bf16x8*)&wsh[(c*8 + t)*512 + l*8];
      acc[t] = __builtin_amdgcn_mfma_f32_16x16x32_bf16(afr[c], b, acc[t], 0, 0, 0);
    }
#pragma unroll
  for (int t = 0; t < 8; t++){
    int col = 128 + t * 16 + m;
#pragma unroll
    for (int r = 0; r < 4; r++){
      int n = row_d + r;
      if (n < N) u[(size_t)n * 256 + col] = __float2bfloat16(acc[t][r]);
    }
  }
}

// ---------------------------------------------------------------------------
// Edge block (R5 final form — proven 54us): 3-barrier GEMM structure +
// register-batched block-level segment reduce.
// ---------------------------------------------------------------------------
__launch_bounds__(512)
__global__ void edge_block(const int* __restrict__ psnd,
                           const int* __restrict__ prcv,
                           const __hip_bfloat16* __restrict__ u,   // [n][256] bf16
                           __hip_bfloat16* __restrict__ ef,
                           const __hip_bfloat16* __restrict__ Wfrag, // eW1|eW2 frag-major
                           const float* __restrict__ b1,
                           const float* __restrict__ b2,
                           float* __restrict__ agg,                 // [N][128] f32, zeroed
                           int do_write, int E){
  __shared__ __align__(16) short bsh[16384];       // 32 KB: W1e, then W2
  __shared__ __align__(16) short hsh[8][16][136];  // 34.8 KB
  __shared__ int rsh[128];                         // receiver per block-edge
  const int tid = threadIdx.x, w = tid >> 6, l = tid & 63, m = l & 15, q = l >> 4;
  const short* wsrc = (const short*)Wfrag;
  const int row0 = blockIdx.x * 128 + w * 16;
  const int grow = min(row0 + (l >> 2), E - 1);
  const int us_row = psnd[grow], ur_row = prcv[grow];
  if ((l & 3) == 0) rsh[w * 16 + (l >> 2)] = ur_row;
#pragma unroll
  for (int i = 0; i < 4; i++){
    int inst = i * 8 + w;
    gl_lds16(wsrc + inst * 512 + l * 8, &bsh[inst * 512]);
  }
  const int ra = min(row0 + m, E - 1);
  const short* pe = (const short*)ef + (size_t)ra * HDIM + q * 8;
  bf16x8 afr[4];
#pragma unroll
  for (int c = 0; c < 4; c++) afr[c] = *(const bf16x8*)(pe + c * 32);
  {
    const short* pus = (const short*)u + (size_t)us_row * 256 + (l & 3) * 32;
    const short* pur = (const short*)u + (size_t)ur_row * 256 + 128 + (l & 3) * 32;
    short* hdst = &hsh[w][l >> 2][(l & 3) * 32];
#pragma unroll
    for (int k = 0; k < 4; k++){
      bf16x8 a = *(const bf16x8*)(pus + k * 8);
      bf16x8 b = *(const bf16x8*)(pur + k * 8);
      bf16x8 s;
#pragma unroll
      for (int j = 0; j < 8; j++) s[j] = f2bf(bfb2f(a[j]) + bfb2f(b[j]));
      *(bf16x8*)(hdst + k * 8) = s;
    }
  }
  f32x4 acc[8];
#pragma unroll
  for (int t = 0; t < 8; t++) acc[t] = (f32x4){0.f,0.f,0.f,0.f};
  __syncthreads();                               // B1: W1e + u-sums ready
#pragma unroll
  for (int c = 0; c < 4; c++){
#pragma unroll
    for (int t = 0; t < 8; t++){
      bf16x8 b = *(const bf16x8*)&bsh[(c*8 + t)*512 + l*8];
      acc[t] = __builtin_amdgcn_mfma_f32_16x16x32_bf16(afr[c], b, acc[t], 0, 0, 0);
    }
  }
  __syncthreads();                               // B2: all waves done with W1e
#pragma unroll
  for (int i = 0; i < 4; i++){
    int inst = i * 8 + w;
    gl_lds16(wsrc + 49152 + inst * 512 + l * 8, &bsh[inst * 512]);
  }
#pragma unroll
  for (int t = 0; t < 8; t++){
    float bb = b1[t * 16 + m];
#pragma unroll
    for (int r = 0; r < 4; r++){
      float uval = bfb2f(hsh[w][q*4 + r][t*16 + m]);
      hsh[w][q*4 + r][t*16 + m] = f2bf(fmaxf(acc[t][r] + uval + bb, 0.f));
    }
  }
  __syncthreads();                               // B3: W2 staged, h ready
  bf16x8 ah[4];
  const short* ph = &hsh[w][m][0] + q * 8;
#pragma unroll
  for (int c = 0; c < 4; c++) ah[c] = *(const bf16x8*)(ph + c * 32);
#pragma unroll
  for (int t = 0; t < 8; t++) acc[t] = (f32x4){0.f,0.f,0.f,0.f};
#pragma unroll
  for (int c = 0; c < 4; c++){
#pragma unroll
    for (int t = 0; t < 8; t++){
      bf16x8 b = *(const bf16x8*)&bsh[(c*8 + t)*512 + l*8];
      acc[t] = __builtin_amdgcn_mfma_f32_16x16x32_bf16(ah[c], b, acc[t], 0, 0, 0);
    }
  }
#pragma unroll
  for (int t = 0; t < 8; t++){
    float bb = b2[t * 16 + m];
#pragma unroll
    for (int r = 0; r < 4; r++)
      hsh[w][q*4 + r][t*16 + m] = f2bf(acc[t][r] + bb);
  }
  const int orow = row0 + (l >> 2);
  const int orc = min(orow, E - 1);
  const short* pold = (const short*)ef + (size_t)orc * HDIM + (l & 3) * 32;
  short* hslot = &hsh[w][l >> 2][(l & 3) * 32];
  short* dst = (short*)ef + (size_t)orc * HDIM + (l & 3) * 32;
  const bool wr = (orow < E) && do_write;
#pragma unroll
  for (int k = 0; k < 4; k++){
    bf16x8 vnew = *(const bf16x8*)(hslot + k * 8);
    bf16x8 vo   = *(const bf16x8*)(pold + k * 8);
    bf16x8 vr;
#pragma unroll
    for (int j = 0; j < 8; j++) vr[j] = f2bf(bfb2f(vnew[j]) + bfb2f(vo[j]));
    *(bf16x8*)(hslot + k * 8) = vr;
    if (wr) *(bf16x8*)(dst + k * 8) = vr;
  }
  __syncthreads();                               // B4: hsh finalized block-wide
  {
    const int c = tid & 127;          // column
    const int g = tid >> 7;           // group 0..3 (uniform per wave)
    const int nval = min(128, E - (int)blockIdx.x * 128);
    const int e0 = g * 32;
    if (e0 < nval){
      const int e1 = min(e0 + 32, nval);
      float run = 0.f; int cur = -1; int runstart = e0;
#pragma unroll
      for (int half = 0; half < 2; half++){
        float v[16]; int rv[16];
#pragma unroll
        for (int k = 0; k < 16; k++){
          int e = e0 + half * 16 + k;
          v[k]  = bfb2f(hsh[(e >> 4) & 7][e & 15][c]);
          rv[k] = rsh[e & 127];
        }
#pragma unroll
        for (int k = 0; k < 16; k++){
          int e = e0 + half * 16 + k;
          if (e < e1){                           // wave-uniform
            if (rv[k] != cur){                   // wave-uniform
              if (cur >= 0){
                if (runstart == e0) atomicAdd(&agg[(size_t)cur * 128 + c], run);
                else                agg[(size_t)cur * 128 + c] = run;
              }
              cur = rv[k]; run = 0.f; runstart = e;
            }
            run += v[k];
          }
        }
      }
      atomicAdd(&agg[(size_t)cur * 128 + c], run);
    }
  }
}

// ---------------------------------------------------------------------------
// Node block (R5 dense form): coalesced agg[N][128] f32 read, W1
// double-buffered 16KB halves, W2 staged overlapped with epilogue-1.
// ---------------------------------------------------------------------------
#define NB_COMPUTE_CHUNK(c) do {                                               \
  const short* bb_ = &bsh[(((c) >> 1) & 1) * 8192 + ((c) & 1) * 4096];         \
  _Pragma("unroll")                                                            \
  for (int t = 0; t < 8; t++){                                                 \
    bf16x8 b = *(const bf16x8*)(bb_ + t * 512 + l * 8);                        \
    acc[t] = __builtin_amdgcn_mfma_f32_16x16x32_bf16(afr[c], b, acc[t], 0, 0, 0); \
  }                                                                            \
} while(0)

__launch_bounds__(256)
__global__ void node_block(const float* __restrict__ agg,   // [N][128] f32
                           __hip_bfloat16* __restrict__ nf,
                           const __hip_bfloat16* __restrict__ Wfrag, // nW1|nW2
                           const float* __restrict__ b1,
                           const float* __restrict__ b2,
                           int N){
  __shared__ __align__(16) short bsh[16384];        // 32 KB: 2 halves x 16 KB
  __shared__ __align__(16) short hsh[4][16][136];   // 17.4 KB
  const int tid = threadIdx.x, w = tid >> 6, l = tid & 63, m = l & 15, q = l >> 4;
  const short* wsrc = (const short*)Wfrag;
  auto stage_pair = [&](int p){
    const short* s = wsrc + p * 8192;
    short* d = &bsh[(p & 1) * 8192];
#pragma unroll
    for (int i = 0; i < 4; i++)
      gl_lds16(s + (i*4 + w)*512 + l*8, d + (i*4 + w)*512);
  };
  stage_pair(0); stage_pair(1);

  const int row0 = blockIdx.x * 64 + w * 16;
  const int ra = min(row0 + m, N - 1);
  const short* pn = (const short*)nf + (size_t)ra * HDIM + q * 8;
  bf16x8 afr[8];
#pragma unroll
  for (int c = 0; c < 4; c++) afr[c] = *(const bf16x8*)(pn + c * 32);

  // dense agg read (coalesced, overlaps the weight DMA above)
  const float* pag = agg + (size_t)ra * 128 + q * 8;
#pragma unroll
  for (int c = 0; c < 4; c++){
    f32x4 a0 = *(const f32x4*)(pag + c * 32);
    f32x4 a1 = *(const f32x4*)(pag + c * 32 + 4);
#pragma unroll
    for (int j = 0; j < 4; j++){
      afr[4 + c][j]     = f2bf(a0[j]);
      afr[4 + c][4 + j] = f2bf(a1[j]);
    }
  }

  f32x4 acc[8];
#pragma unroll
  for (int t = 0; t < 8; t++) acc[t] = (f32x4){0.f,0.f,0.f,0.f};
  __syncthreads();                   // B1: pairs 0,1 staged
  NB_COMPUTE_CHUNK(0);
  NB_COMPUTE_CHUNK(1);
  __syncthreads();                   // B2: half0 free
  stage_pair(2);
  NB_COMPUTE_CHUNK(2);
  NB_COMPUTE_CHUNK(3);
  __syncthreads();                   // B3: half1 free, pair2 staged
  stage_pair(3);
  NB_COMPUTE_CHUNK(4);
  NB_COMPUTE_CHUNK(5);
  __syncthreads();                   // B4: pair3 staged
  NB_COMPUTE_CHUNK(6);
  NB_COMPUTE_CHUNK(7);
  __syncthreads();                   // B5: all waves done with W1
  {
    const short* s = wsrc + 32768;   // W2
#pragma unroll
    for (int i = 0; i < 8; i++)
      gl_lds16(s + (i*4 + w)*512 + l*8, &bsh[(i*4 + w)*512]);
  }
#pragma unroll
  for (int t = 0; t < 8; t++){
    float bb = b1[t * 16 + m];
#pragma unroll
    for (int r = 0; r < 4; r++)
      hsh[w][q*4 + r][t*16 + m] = f2bf(fmaxf(acc[t][r] + bb, 0.f));
  }
  __syncthreads();                   // B6: W2 staged
  const short* ph = &hsh[w][m][0] + q * 8;
#pragma unroll
  for (int t = 0; t < 8; t++) acc[t] = (f32x4){0.f,0.f,0.f,0.f};
#pragma unroll
  for (int c = 0; c < 4; c++){
    bf16x8 a = *(const bf16x8*)(ph + c * 32);
#pragma unroll
    for (int t = 0; t < 8; t++){
      bf16x8 b = *(const bf16x8*)&bsh[(c*8 + t)*512 + l*8];
      acc[t] = __builtin_amdgcn_mfma_f32_16x16x32_bf16(a, b, acc[t], 0, 0, 0);
    }
  }
#pragma unroll
  for (int t = 0; t < 8; t++){
    float bb = b2[t * 16 + m];
#pragma unroll
    for (int r = 0; r < 4; r++)
      hsh[w][q*4 + r][t*16 + m] = f2bf(acc[t][r] + bb);
  }
  const int orow = row0 + (l >> 2);
  if (orow < N){
    const short* pold = (const short*)nf + (size_t)orow * HDIM + (l & 3) * 32;
    const short* src = &hsh[w][l >> 2][(l & 3) * 32];
    short* dst = (short*)nf + (size_t)orow * HDIM + (l & 3) * 32;
#pragma unroll
    for (int k = 0; k < 4; k++){
      bf16x8 vnew = *(const bf16x8*)(src + k * 8);
      bf16x8 vo   = *(const bf16x8*)(pold + k * 8);
      bf16x8 vr;
#pragma unroll
      for (int j = 0; j < 8; j++) vr[j] = f2bf(bfb2f(vnew[j]) + bfb2f(vo[j]));
      *(bf16x8*)(dst + k * 8) = vr;
    }
  }
}

// ---------------------------------------------------------------------------
// dec_fused (R5 form): decoder layer1 (MFMA) + layer2 (shfl-reduce) + loss
// ---------------------------------------------------------------------------
__launch_bounds__(256)
__global__ void dec_fused(const __hip_bfloat16* __restrict__ A,   // nf
                          const __hip_bfloat16* __restrict__ Wf,  // decW1 frag-major
                          const float* __restrict__ b1,
                          const float* __restrict__ W2,            // [128][3]
                          const float* __restrict__ b2,            // [3]
                          const float* __restrict__ zl,
                          const float* __restrict__ z_target,
                          const float* __restrict__ fin,
                          float* __restrict__ d_out,
                          float* __restrict__ lred,                // 4 floats, zeroed
                          unsigned int* __restrict__ cnt,          // zeroed
                          int N){
  __shared__ __align__(16) short bsh[16384];
  __shared__ float Wl[HDIM * 3];
  __shared__ float red[4][4];
  const int tid = threadIdx.x, w = tid >> 6, l = tid & 63, m = l & 15, q = l >> 4;
  const short* wsrc = (const short*)Wf;
#pragma unroll
  for (int i = 0; i < 8; i++){
    int inst = w * 8 + i;
    gl_lds16(wsrc + inst * 512 + l * 8, &bsh[inst * 512]);
  }
  for (int i = tid; i < HDIM * 3; i += 256) Wl[i] = W2[i];
  const int row0 = blockIdx.x * 64 + w * 16;
  const int ra = min(row0 + m, N - 1);
  const short* pa = (const short*)A + (size_t)ra * HDIM + q * 8;
  bf16x8 afr[4];
#pragma unroll
  for (int c = 0; c < 4; c++) afr[c] = *(const bf16x8*)(pa + c * 32);
  f32x4 acc[8];
#pragma unroll
  for (int t = 0; t < 8; t++) acc[t] = (f32x4){0.f,0.f,0.f,0.f};
  __syncthreads();
#pragma unroll
  for (int c = 0; c < 4; c++){
#pragma unroll
    for (int t = 0; t < 8; t++){
      bf16x8 b = *(const bf16x8*)&bsh[(c*8 + t)*512 + l*8];
      acc[t] = __builtin_amdgcn_mfma_f32_16x16x32_bf16(afr[c], b, acc[t], 0, 0, 0);
    }
  }
  float p0[4] = {0,0,0,0}, p1[4] = {0,0,0,0}, p2[4] = {0,0,0,0};
#pragma unroll
  for (int t = 0; t < 8; t++){
    int col = t * 16 + m;
    float bb = b1[col];
    float w0 = Wl[col*3], w1 = Wl[col*3+1], w2 = Wl[col*3+2];
#pragma unroll
    for (int r = 0; r < 4; r++){
      float h = fmaxf(acc[t][r] + bb, 0.f);
      p0[r] += h * w0; p1[r] += h * w1; p2[r] += h * w2;
    }
  }
#pragma unroll
  for (int r = 0; r < 4; r++){
#pragma unroll
    for (int o = 1; o < 16; o <<= 1){
      p0[r] += __shfl_xor(p0[r], o, 64);
      p1[r] += __shfl_xor(p1[r], o, 64);
      p2[r] += __shfl_xor(p2[r], o, 64);
    }
  }
  float s[4] = {0.f,0.f,0.f,0.f};
  if (m == 0){
#pragma unroll
    for (int r = 0; r < 4; r++){
      int n = row0 + q * 4 + r;
      if (n < N){
        float pd[3] = {p0[r], p1[r], p2[r]};
#pragma unroll
        for (int d = 0; d < 3; d++){
          float o   = pd[d] + b2[d];
          float om = fin[12 + d], os = fin[15 + d];
          float zld = zl[3*n + d];
          float zt  = z_target[3*n + d];
          float tn  = ((zt - zld) - om) / os;
          float diff = tn - o;
          s[0] += diff * diff;
          float zp = zld + o * os + om;
          d_out[3*n + d] = zp;
          float e = zp - zt;
          s[1 + d] += e * e;
        }
      }
    }
  }
#pragma unroll
  for (int k = 0; k < 4; k++) s[k] = wave_sum(s[k]);
  if (l == 0)
#pragma unroll
    for (int k = 0; k < 4; k++) red[w][k] = s[k];
  __syncthreads();
  if (tid < 4)
    atomicAdd(&lred[tid], red[0][tid] + red[1][tid] + red[2][tid] + red[3][tid]);
  __syncthreads();
  if (tid == 0){
    __threadfence();
    unsigned int t = atomicAdd(cnt, 1u);
    if (t == gridDim.x - 1){
      float vals[4];
#pragma unroll
      for (int k = 0; k < 4; k++) vals[k] = atomicAdd(&lred[k], 0.f);
      float cN = (float)N;
      float loss = vals[0] / (3.f * cN);
      float rmse = (sqrtf(vals[1]/cN) + sqrtf(vals[2]/cN) + sqrtf(vals[3]/cN)) / 3.f;
      d_out[(size_t)3 * N]     = loss;
      d_out[(size_t)3 * N + 1] = rmse;
    }
  }
}

// ---------------------------------------------------------------------------
extern "C" void kernel_launch(void* const* d_in, const int* in_sizes, int n_in,
                              void* d_out, int out_size, void* d_ws, size_t ws_size,
                              hipStream_t stream){
  const float* z           = (const float*)d_in[0];
  const float* z_target    = (const float*)d_in[1];
  const float* pos         = (const float*)d_in[2];
  const float* enc_node_W1 = (const float*)d_in[3];
  const float* enc_node_b1 = (const float*)d_in[4];
  const float* enc_node_W2 = (const float*)d_in[5];
  const float* enc_node_b2 = (const float*)d_in[6];
  const float* enc_edge_W1 = (const float*)d_in[7];
  const float* enc_edge_b1 = (const float*)d_in[8];
  const float* enc_edge_W2 = (const float*)d_in[9];
  const float* enc_edge_b2 = (const float*)d_in[10];
  const float* dec_W1      = (const float*)d_in[11];
  const float* dec_b1      = (const float*)d_in[12];
  const float* dec_W2      = (const float*)d_in[13];
  const float* dec_b2      = (const float*)d_in[14];
  const float* blk_edge_W1 = (const float*)d_in[15];
  const float* blk_edge_b1 = (const float*)d_in[16];
  const float* blk_edge_W2 = (const float*)d_in[17];
  const float* blk_edge_b2 = (const float*)d_in[18];
  const float* blk_node_W1 = (const float*)d_in[19];
  const float* blk_node_b1 = (const float*)d_in[20];
  const float* blk_node_W2 = (const float*)d_in[21];
  const float* blk_node_b2 = (const float*)d_in[22];
  const int*   senders     = (const int*)d_in[23];
  const int*   receivers   = (const int*)d_in[24];

  const int N = in_sizes[1] / 3;
  const int E = in_sizes[23];
  const float* zl = z + (size_t)N * 3;

  const int neb = ceil_div(E, TPB);
  const int nnb = ceil_div(N, TPB);
  const int nsb = ceil_div(N, 1024);   // scan blocks
  const int EB  = ceil_div(E, 64);
  const int NB  = ceil_div(N, 64);

  char* p = (char*)d_ws;
  auto carve = [&](size_t bytes) -> char* {
    char* r = p; p += (bytes + 255) & ~(size_t)255; return r;
  };
  float* stats_fin = (float*)carve(32 * 4);
  float* epart     = (float*)carve((size_t)neb * 6 * 4);
  float* npart     = (float*)carve((size_t)nnb * 12 * 4);
  float* ef_raw    = (float*)carve((size_t)E * 3 * 4);
  int*   deg       = (int*)carve((size_t)(N + 16) * 4);   // + lred(4f) + cnt
  float* lred      = (float*)(deg + N);
  unsigned int* cnt = (unsigned int*)(deg + N + 4);
  int*   bsum      = (int*)carve((size_t)(nsb + 1) * 4);
  int*   cursor    = (int*)carve((size_t)N * 4);
  int*   psnd      = (int*)carve((size_t)E * 4);
  int*   prcv      = (int*)carve((size_t)E * 4);
  float* agg       = (float*)carve(((size_t)N + 64) * 128 * 4);  // padded
  __hip_bfloat16* wp = (__hip_bfloat16*)carve((size_t)507904 * 2);
  __hip_bfloat16* ef = (__hip_bfloat16*)carve((size_t)E * HDIM * 2);
  __hip_bfloat16* nf = (__hip_bfloat16*)carve((size_t)N * HDIM * 2);
  __hip_bfloat16* u  = (__hip_bfloat16*)carve((size_t)N * 256 * 2);

  float* out = (float*)d_out;

  hipMemsetAsync(deg, 0, (size_t)(N + 16) * 4, stream);

  prep_a<<<neb + nnb + 3648, TPB, 0, stream>>>(receivers, deg, E, neb,
                                               zl, z_target, npart, N, nnb,
                                               enc_edge_W2, enc_node_W2, dec_W1,
                                               blk_edge_W1, blk_edge_W2,
                                               blk_node_W1, blk_node_W2, wp);
  scan_pass1<<<nsb, TPB, 0, stream>>>(deg, bsum, N);
  scan_pass3<<<nsb, TPB, 0, stream>>>(deg, bsum, nsb, cursor, N);
  edge_prep<<<neb, TPB, 0, stream>>>(pos, senders, receivers, cursor,
                                     psnd, prcv, ef_raw, epart, E);
  reduce_finalize<<<1, TPB, 0, stream>>>(epart, neb, npart, nnb, stats_fin, E, N);

  encoder_both<<<EB + NB, TPB, 0, stream>>>(ef_raw, zl, stats_fin,
                                            enc_edge_W1, enc_edge_b1,
                                            enc_node_W1, enc_node_b1,
                                            wp, enc_edge_b2, enc_node_b2,
                                            ef, nf, E, N, EB);

  for (int b = 0; b < 4; b++){
    const __hip_bfloat16* eWf = wp + 49152 + (size_t)b * 114688;   // eW1|eW2
    const __hip_bfloat16* nWf = eWf + 65536;                       // nW1|nW2
    const float* eb1 = blk_edge_b1 + (size_t)b * 128;
    const float* eb2 = blk_edge_b2 + (size_t)b * 128;
    const float* nb1 = blk_node_b1 + (size_t)b * 128;
    const float* nb2 = blk_node_b2 + (size_t)b * 128;

    msg_pre<<<NB, TPB, 0, stream>>>(nf, eWf, u, agg, N);
    edge_block<<<ceil_div(E, 128), 512, 0, stream>>>(psnd, prcv, u, ef,
                                                     eWf, eb1, eb2, agg,
                                                     (b < 3) ? 1 : 0, E);
    node_block<<<NB, TPB, 0, stream>>>(agg, nf, nWf, nb1, nb2, N);
  }

  dec_fused<<<NB, TPB, 0, stream>>>(nf, wp + 32768, dec_b1, dec_W2, dec_b2,
                                    zl, z_target, stats_fin,
                                    out, lred, cnt, N);
}